// Round 11
// baseline (290.383 us; speedup 1.0000x reference)
//
#include <hip/hip_runtime.h>

#define NN 50000
#define MPAD 50048   // 391 * 128 = 782 * 64
#define ICH 256
#define HID 64
#define HEADS 4
#define OCH 40
#define NE 800000
#define ETOT (NE + NN)
#define SLOPE 0.2f
#define LDP 40       // padded LDS row stride (bf16 elems): 32 data + 8 pad
#define SCAN_B 196   // 196 * 256 = 50176 >= NN
#define HB ((ETOT + 255) / 256)

typedef __bf16 v8bf __attribute__((ext_vector_type(8)));
typedef float v4f __attribute__((ext_vector_type(4)));

// ---- prep: blocks [0,384) transpose W1/W2 to bf16; blocks [384, ...) hist --
// deg must be zeroed (memset) BEFORE this kernel.
__global__ __launch_bounds__(256) void prep_kernel(
        const float* __restrict__ W1, const float* __restrict__ W2,
        __bf16* __restrict__ W1T, __bf16* __restrict__ W2T,
        const int* __restrict__ dstArr, int* __restrict__ deg,
        int* __restrict__ rank) {
    int blk = blockIdx.x;
    if (blk < 384) {
        int i = blk * 256 + threadIdx.x;  // 0..98303
        if (i < 65536) {
            int n = i >> 8, k = i & 255;
            W1T[n * 256 + k] = (__bf16)W1[k * 256 + n];
        } else {
            int j = i - 65536;  // 0..32767
            int n = j >> 8, k = j & 255;
            W2T[n * 256 + k] = (n < OCH) ? (__bf16)W2[k * OCH + n] : (__bf16)0.f;
        }
    } else {
        int i = (blk - 384) * 256 + threadIdx.x;
        if (i < ETOT) {
            int d = (i < NE) ? dstArr[i] : (i - NE);
            rank[i] = atomicAdd(&deg[d], 1);
        }
    }
}

__global__ __launch_bounds__(256) void blocksum_kernel(const int* __restrict__ deg,
                                                       int* __restrict__ bsum) {
    __shared__ int wsum[4];
    int i = blockIdx.x * 256 + threadIdx.x;
    int v = (i < NN) ? deg[i] : 0;
#pragma unroll
    for (int m = 1; m <= 32; m <<= 1) v += __shfl_xor(v, m, 64);
    if ((threadIdx.x & 63) == 0) wsum[threadIdx.x >> 6] = v;
    __syncthreads();
    if (threadIdx.x == 0) bsum[blockIdx.x] = wsum[0] + wsum[1] + wsum[2] + wsum[3];
}

__global__ __launch_bounds__(256) void scan_final(const int* __restrict__ deg,
                                                  const int* __restrict__ bsum,
                                                  int* __restrict__ offs) {
    __shared__ int wsum[4];
    int t = threadIdx.x;
    int lane = t & 63, w = t >> 6;
    int pv = (t < blockIdx.x) ? bsum[t] : 0;  // blockIdx.x <= 195 < 256
#pragma unroll
    for (int m = 1; m <= 32; m <<= 1) pv += __shfl_xor(pv, m, 64);
    if (lane == 0) wsum[w] = pv;
    __syncthreads();
    int base = wsum[0] + wsum[1] + wsum[2] + wsum[3];
    __syncthreads();
    int i = blockIdx.x * 256 + t;
    int v = (i < NN) ? deg[i] : 0;
    int x = v;
#pragma unroll
    for (int off = 1; off < 64; off <<= 1) {
        int tt = __shfl_up(x, off, 64);
        if (lane >= off) x += tt;
    }
    if (lane == 63) wsum[w] = x;
    __syncthreads();
    int wbase = 0;
    for (int k = 0; k < w; k++) wbase += wsum[k];
    int excl = base + wbase + x - v;
    if (i < NN) {
        offs[i] = excl;
        if (i == NN - 1) offs[NN] = excl + v;
    }
}

__global__ void scatter_kernel(const int* __restrict__ srcArr, const int* __restrict__ dstArr,
                               const int* __restrict__ offs, const int* __restrict__ rank,
                               int* __restrict__ csr) {
    int i = blockIdx.x * blockDim.x + threadIdx.x;
    if (i < ETOT) {
        int s, d;
        if (i < NE) {
            s = srcArr[i];
            d = dstArr[i];
        } else {
            s = d = i - NE;
        }
        csr[offs[d] + rank[i]] = s;
    }
}

// ---- layer-1 GEMM: 64-row x 256-col tiles, grid=782, x read once,
//      fp32->bf16 in-register staging, al1 epilogue -------------------------
__global__ __launch_bounds__(256) void gemm1_fused(
        const float* __restrict__ X, const __bf16* __restrict__ B,
        __bf16* __restrict__ C, const float* __restrict__ a_s,
        const float* __restrict__ a_d, float* __restrict__ alsrc,
        float* __restrict__ aldst) {
    __shared__ __bf16 As[64 * LDP];
    __shared__ __bf16 Bs[256 * LDP];
    int tid = threadIdx.x;
    int lane = tid & 63, wid = tid >> 6;
    int quad = lane >> 4, l15 = lane & 15;
    int wn = wid * 64;               // each wave: 64 rows x 64 cols (one head)
    long row0 = (long)blockIdx.x * 64;
    v4f acc[4][4] = {};
    for (int k0 = 0; k0 < 256; k0 += 32) {
        {   // stage A: 64 rows x 32 k, fp32 -> bf16, one uint4 per thread
            int r = tid >> 2, q = tid & 3;
            long row = row0 + r;
            union { __bf16 hh[8]; uint4 u; } pk;
            if (row < NN) {
                const float4* p = (const float4*)(X + row * ICH + k0 + q * 8);
                float4 f0 = p[0], f1 = p[1];
                pk.hh[0] = (__bf16)f0.x; pk.hh[1] = (__bf16)f0.y;
                pk.hh[2] = (__bf16)f0.z; pk.hh[3] = (__bf16)f0.w;
                pk.hh[4] = (__bf16)f1.x; pk.hh[5] = (__bf16)f1.y;
                pk.hh[6] = (__bf16)f1.z; pk.hh[7] = (__bf16)f1.w;
            } else {
                pk.u = uint4{0u, 0u, 0u, 0u};
            }
            *(uint4*)(&As[r * LDP + q * 8]) = pk.u;
        }
#pragma unroll
        for (int t = 0; t < 4; t++) {  // stage B: 256 cols x 32 k
            int i = tid + t * 256;
            int r = i >> 2, q = i & 3;
            *(uint4*)(&Bs[r * LDP + q * 8]) = *(const uint4*)(B + (size_t)r * 256 + k0 + q * 8);
        }
        __syncthreads();
        v8bf af[4], bfr[4];
#pragma unroll
        for (int t = 0; t < 4; t++) {
            af[t]  = *(const v8bf*)(&As[(t * 16 + l15) * LDP + quad * 8]);
            bfr[t] = *(const v8bf*)(&Bs[(wn + t * 16 + l15) * LDP + quad * 8]);
        }
#pragma unroll
        for (int mi = 0; mi < 4; mi++)
#pragma unroll
            for (int ni = 0; ni < 4; ni++)
                acc[mi][ni] = __builtin_amdgcn_mfma_f32_16x16x32_bf16(af[mi], bfr[ni], acc[mi][ni], 0, 0, 0);
        __syncthreads();
    }
#pragma unroll
    for (int mi = 0; mi < 4; mi++)
#pragma unroll
        for (int ni = 0; ni < 4; ni++)
#pragma unroll
            for (int r = 0; r < 4; r++) {
                long row = row0 + mi * 16 + quad * 4 + r;
                C[row * ICH + wn + ni * 16 + l15] = (__bf16)acc[mi][ni][r];
            }
    int head = wn >> 6;
    float asv[4], adv[4];
#pragma unroll
    for (int ni = 0; ni < 4; ni++) {
        int cc = wn + ni * 16 + l15;
        asv[ni] = a_s[cc];
        adv[ni] = a_d[cc];
    }
#pragma unroll
    for (int mi = 0; mi < 4; mi++)
#pragma unroll
        for (int r = 0; r < 4; r++) {
            float vs = 0.f, vd = 0.f;
#pragma unroll
            for (int ni = 0; ni < 4; ni++) {
                vs += acc[mi][ni][r] * asv[ni];
                vd += acc[mi][ni][r] * adv[ni];
            }
#pragma unroll
            for (int m = 1; m <= 8; m <<= 1) {
                vs += __shfl_xor(vs, m, 64);
                vd += __shfl_xor(vd, m, 64);
            }
            long row = row0 + mi * 16 + quad * 4 + r;
            if (l15 == 0 && row < NN) {
                alsrc[row * HEADS + head] = vs;
                aldst[row * HEADS + head] = vd;
            }
        }
}

// ---- layer-2 GEMM: 64-row x 128-col tiles, grid=782; compact 40-col C;
//      al2 epilogue --------------------------------------------------------
__global__ __launch_bounds__(256) void gemm2_fused(
        const __bf16* __restrict__ A, const __bf16* __restrict__ B,
        __bf16* __restrict__ C, const float* __restrict__ a_s,
        const float* __restrict__ a_d, float* __restrict__ alsrc,
        float* __restrict__ aldst) {
    __shared__ __bf16 As[64 * LDP];
    __shared__ __bf16 Bs[128 * LDP];
    int tid = threadIdx.x;
    int lane = tid & 63, wid = tid >> 6;
    int quad = lane >> 4, l15 = lane & 15;
    int wm = (wid >> 1) * 32, wn = (wid & 1) * 64;  // wave: 32 rows x 64 cols
    long row0 = (long)blockIdx.x * 64;
    v4f acc[2][4] = {};
    for (int k0 = 0; k0 < 256; k0 += 32) {
        {
            int r = tid >> 2, q = tid & 3;
            *(uint4*)(&As[r * LDP + q * 8]) = *(const uint4*)(A + (row0 + r) * 256 + k0 + q * 8);
        }
#pragma unroll
        for (int t = 0; t < 2; t++) {
            int i = tid + t * 256;
            int r = i >> 2, q = i & 3;
            *(uint4*)(&Bs[r * LDP + q * 8]) = *(const uint4*)(B + (size_t)r * 256 + k0 + q * 8);
        }
        __syncthreads();
        v8bf af[2], bfr[4];
#pragma unroll
        for (int t = 0; t < 2; t++)
            af[t] = *(const v8bf*)(&As[(wm + t * 16 + l15) * LDP + quad * 8]);
#pragma unroll
        for (int t = 0; t < 4; t++)
            bfr[t] = *(const v8bf*)(&Bs[(wn + t * 16 + l15) * LDP + quad * 8]);
#pragma unroll
        for (int mi = 0; mi < 2; mi++)
#pragma unroll
            for (int ni = 0; ni < 4; ni++)
                acc[mi][ni] = __builtin_amdgcn_mfma_f32_16x16x32_bf16(af[mi], bfr[ni], acc[mi][ni], 0, 0, 0);
        __syncthreads();
    }
#pragma unroll
    for (int mi = 0; mi < 2; mi++)
#pragma unroll
        for (int ni = 0; ni < 4; ni++)
#pragma unroll
            for (int r = 0; r < 4; r++) {
                long row = row0 + wm + mi * 16 + quad * 4 + r;
                int col = wn + ni * 16 + l15;
                if (col < OCH) C[row * OCH + col] = (__bf16)acc[mi][ni][r];
            }
    if (wn == 0) {
        float asv[4], adv[4];
#pragma unroll
        for (int ni = 0; ni < 4; ni++) {
            int c = ni * 16 + l15;
            bool on = c < OCH;
            asv[ni] = on ? a_s[c] : 0.f;
            adv[ni] = on ? a_d[c] : 0.f;
        }
#pragma unroll
        for (int mi = 0; mi < 2; mi++)
#pragma unroll
            for (int r = 0; r < 4; r++) {
                float vs = 0.f, vd = 0.f;
#pragma unroll
                for (int ni = 0; ni < 4; ni++) {
                    vs += acc[mi][ni][r] * asv[ni];
                    vd += acc[mi][ni][r] * adv[ni];
                }
#pragma unroll
                for (int m = 1; m <= 8; m <<= 1) {
                    vs += __shfl_xor(vs, m, 64);
                    vd += __shfl_xor(vd, m, 64);
                }
                long row = row0 + wm + mi * 16 + quad * 4 + r;
                if (l15 == 0 && row < NN) {
                    alsrc[row] = vs;
                    aldst[row] = vd;
                }
            }
    }
}

// -------- layer-1 aggregation: wave/dst; 2 edge-slots x 32 cg; pipelined ---
// d0: dst-range offset (grid split for profiler visibility)
__global__ __launch_bounds__(256) void aggregate1(
        const int* __restrict__ offs, const int* __restrict__ csr,
        const __bf16* __restrict__ h, const float* __restrict__ alsrc,
        const float* __restrict__ aldst, const float* __restrict__ bias,
        __bf16* __restrict__ z, int d0) {
    int lane = threadIdx.x & 63, wid = threadIdx.x >> 6;
    int d = d0 + blockIdx.x * 4 + wid;
    if (d >= MPAD) return;
    int es = lane >> 5;
    int cg = lane & 31;
    if (d >= NN) {
        if (es == 0) *(uint4*)(z + (size_t)d * ICH + cg * 8) = uint4{0u, 0u, 0u, 0u};
        return;
    }
    int head = cg >> 3;
    int e0 = offs[d], e1 = offs[d + 1];
    float ald = aldst[d * HEADS + head];
    float acc[8] = {};
    float wsum = 0.f;
    int e = e0 + es;
    int sA = (e < e1) ? csr[e] : 0;
    float alA = alsrc[sA * HEADS + head];
    v8bf hvA = *(const v8bf*)(h + (size_t)sA * ICH + cg * 8);
    for (; e < e1; e += 2) {
        int en = e + 2;
        int sB = (en < e1) ? csr[en] : 0;
        float alB = alsrc[sB * HEADS + head];
        v8bf hvB = *(const v8bf*)(h + (size_t)sB * ICH + cg * 8);
        float x = alA + ald;
        x = (x > 0.f) ? x : SLOPE * x;
        float w = __expf(x);
        wsum += w;
#pragma unroll
        for (int j = 0; j < 8; j++) acc[j] += w * (float)hvA[j];
        alA = alB; hvA = hvB;
    }
#pragma unroll
    for (int j = 0; j < 8; j++) acc[j] += __shfl_down(acc[j], 32, 64);
    wsum += __shfl_down(wsum, 32, 64);
    if (es == 0) {
        float inv = 1.f / (wsum + 1e-16f);
        union { __bf16 hh[8]; uint4 u; } p;
#pragma unroll
        for (int j = 0; j < 8; j++) {
            float o = acc[j] * inv + bias[cg * 8 + j];
            o = (o > 0.f) ? o : (__expf(o) - 1.f);  // ELU
            p.hh[j] = (__bf16)o;
        }
        *(uint4*)(z + (size_t)d * ICH + cg * 8) = p.u;
    }
}

// -------- layer-2 aggregation: wave/dst; 8 edge-slots x 8 cg; compact h2 ---
__global__ __launch_bounds__(256) void aggregate2(
        const int* __restrict__ offs, const int* __restrict__ csr,
        const __bf16* __restrict__ h2, const float* __restrict__ alsrc,
        const float* __restrict__ aldst, const float* __restrict__ bias,
        float* __restrict__ out) {
    int lane = threadIdx.x & 63, wid = threadIdx.x >> 6;
    int d = blockIdx.x * 4 + wid;
    if (d >= NN) return;
    int es = lane >> 3;
    int cg = lane & 7;
    bool on = cg < 5;
    int cgc = on ? cg : 4;
    int e0 = offs[d], e1 = offs[d + 1];
    float ald = aldst[d];
    float acc[8] = {};
    float wsum = 0.f;
    int e = e0 + es;
    int sA = (e < e1) ? csr[e] : 0;
    float alA = alsrc[sA];
    v8bf hvA = *(const v8bf*)(h2 + (size_t)sA * OCH + cgc * 8);
    for (; e < e1; e += 8) {
        int en = e + 8;
        int sB = (en < e1) ? csr[en] : 0;
        float alB = alsrc[sB];
        v8bf hvB = *(const v8bf*)(h2 + (size_t)sB * OCH + cgc * 8);
        float x = alA + ald;
        x = (x > 0.f) ? x : SLOPE * x;
        float w = __expf(x);
        wsum += w;
#pragma unroll
        for (int j = 0; j < 8; j++) acc[j] += w * (float)hvA[j];
        alA = alB; hvA = hvB;
    }
#pragma unroll
    for (int m = 8; m <= 32; m <<= 1) {
#pragma unroll
        for (int j = 0; j < 8; j++) acc[j] += __shfl_xor(acc[j], m, 64);
        wsum += __shfl_xor(wsum, m, 64);
    }
    if (es == 0 && on) {
        float inv = 1.f / (wsum + 1e-16f);
#pragma unroll
        for (int j = 0; j < 8; j++)
            out[(size_t)d * OCH + cg * 8 + j] = acc[j] * inv + bias[cg * 8 + j];
    }
}

extern "C" void kernel_launch(void* const* d_in, const int* in_sizes, int n_in,
                              void* d_out, int out_size, void* d_ws, size_t ws_size,
                              hipStream_t stream) {
    const float* x   = (const float*)d_in[0];
    const int*   ei  = (const int*)d_in[1];
    const float* W1  = (const float*)d_in[2];
    const float* as1 = (const float*)d_in[3];
    const float* ad1 = (const float*)d_in[4];
    const float* b1  = (const float*)d_in[5];
    const float* W2  = (const float*)d_in[6];
    const float* as2 = (const float*)d_in[7];
    const float* ad2 = (const float*)d_in[8];
    const float* b2  = (const float*)d_in[9];
    float* out = (float*)d_out;

    char* ws = (char*)d_ws;
    size_t o = 0;
    auto alloc = [&](size_t bytes) {
        void* p = ws + o;
        o += (bytes + 255) & ~(size_t)255;
        return p;
    };
    __bf16* h1    = (__bf16*)alloc((size_t)MPAD * ICH * 2);
    __bf16* z     = (__bf16*)alloc((size_t)MPAD * ICH * 2);
    __bf16* h2    = (__bf16*)alloc((size_t)MPAD * OCH * 2);
    __bf16* W1T   = (__bf16*)alloc((size_t)256 * 256 * 2);
    __bf16* W2T   = (__bf16*)alloc((size_t)128 * 256 * 2);
    float* alsrc1 = (float*)alloc((size_t)NN * HEADS * 4);
    float* aldst1 = (float*)alloc((size_t)NN * HEADS * 4);
    float* alsrc2 = (float*)alloc((size_t)NN * 4);
    float* aldst2 = (float*)alloc((size_t)NN * 4);
    int*   deg    = (int*)alloc((size_t)NN * 4);
    int*   offs   = (int*)alloc((size_t)(NN + 1) * 4);
    int*   csr    = (int*)alloc((size_t)ETOT * 4);
    int*   rank   = (int*)alloc((size_t)ETOT * 4);
    int*   bsum   = (int*)alloc((size_t)SCAN_B * 4);

    const int* srcArr = ei;
    const int* dstArr = ei + NE;

    // deg must be zero before prep's hist branch
    hipMemsetAsync(deg, 0, (size_t)NN * 4, stream);

    // prep: transW || hist (task-parallel block ranges)
    prep_kernel<<<384 + HB, 256, 0, stream>>>(W1, W2, W1T, W2T, dstArr, deg, rank);
    blocksum_kernel<<<SCAN_B, 256, 0, stream>>>(deg, bsum);
    scan_final<<<SCAN_B, 256, 0, stream>>>(deg, bsum, offs);
    scatter_kernel<<<HB, 256, 0, stream>>>(srcArr, dstArr, offs, rank, csr);

    // Layer 1 (gemm + al1 fused; aggregate1 split in two for profiler
    // visibility of tier-2 kernels — see session notes)
    gemm1_fused<<<MPAD / 64, 256, 0, stream>>>(x, W1T, h1, as1, ad1, alsrc1, aldst1);
    aggregate1<<<MPAD / 8, 256, 0, stream>>>(offs, csr, h1, alsrc1, aldst1, b1, z, 0);
    aggregate1<<<MPAD / 8, 256, 0, stream>>>(offs, csr, h1, alsrc1, aldst1, b1, z, MPAD / 2);

    // Layer 2
    gemm2_fused<<<MPAD / 64, 256, 0, stream>>>(z, W2T, h2, as2, ad2, alsrc2, aldst2);
    aggregate2<<<(NN + 3) / 4, 256, 0, stream>>>(offs, csr, h2, alsrc2, aldst2, b2, out);
}

// Round 12
// 285.653 us; speedup vs baseline: 1.0166x; 1.0166x over previous
//
#include <hip/hip_runtime.h>

#define NN 50000
#define MPAD 50048   // 1564 * 32
#define ICH 256
#define HID 64
#define HEADS 4
#define OCH 40
#define NE 800000
#define ETOT (NE + NN)
#define SLOPE 0.2f
#define LDP 40       // padded LDS row stride (bf16 elems): 32 data + 8 pad
#define SCAN_B 196   // 196 * 256 = 50176 >= NN
#define HB ((ETOT + 255) / 256)

typedef __bf16 v8bf __attribute__((ext_vector_type(8)));
typedef float v4f __attribute__((ext_vector_type(4)));

// ---- prep: blocks [0,384) transpose W1/W2 to bf16; blocks [384, ...) hist --
// deg must be zeroed (memset) BEFORE this kernel.
__global__ __launch_bounds__(256) void prep_kernel(
        const float* __restrict__ W1, const float* __restrict__ W2,
        __bf16* __restrict__ W1T, __bf16* __restrict__ W2T,
        const int* __restrict__ dstArr, int* __restrict__ deg,
        int* __restrict__ rank) {
    int blk = blockIdx.x;
    if (blk < 384) {
        int i = blk * 256 + threadIdx.x;  // 0..98303
        if (i < 65536) {
            int n = i >> 8, k = i & 255;
            W1T[n * 256 + k] = (__bf16)W1[k * 256 + n];
        } else {
            int j = i - 65536;  // 0..32767
            int n = j >> 8, k = j & 255;
            W2T[n * 256 + k] = (n < OCH) ? (__bf16)W2[k * OCH + n] : (__bf16)0.f;
        }
    } else {
        int i = (blk - 384) * 256 + threadIdx.x;
        if (i < ETOT) {
            int d = (i < NE) ? dstArr[i] : (i - NE);
            rank[i] = atomicAdd(&deg[d], 1);
        }
    }
}

__global__ __launch_bounds__(256) void blocksum_kernel(const int* __restrict__ deg,
                                                       int* __restrict__ bsum) {
    __shared__ int wsum[4];
    int i = blockIdx.x * 256 + threadIdx.x;
    int v = (i < NN) ? deg[i] : 0;
#pragma unroll
    for (int m = 1; m <= 32; m <<= 1) v += __shfl_xor(v, m, 64);
    if ((threadIdx.x & 63) == 0) wsum[threadIdx.x >> 6] = v;
    __syncthreads();
    if (threadIdx.x == 0) bsum[blockIdx.x] = wsum[0] + wsum[1] + wsum[2] + wsum[3];
}

__global__ __launch_bounds__(256) void scan_final(const int* __restrict__ deg,
                                                  const int* __restrict__ bsum,
                                                  int* __restrict__ offs) {
    __shared__ int wsum[4];
    int t = threadIdx.x;
    int lane = t & 63, w = t >> 6;
    int pv = (t < blockIdx.x) ? bsum[t] : 0;  // blockIdx.x <= 195 < 256
#pragma unroll
    for (int m = 1; m <= 32; m <<= 1) pv += __shfl_xor(pv, m, 64);
    if (lane == 0) wsum[w] = pv;
    __syncthreads();
    int base = wsum[0] + wsum[1] + wsum[2] + wsum[3];
    __syncthreads();
    int i = blockIdx.x * 256 + t;
    int v = (i < NN) ? deg[i] : 0;
    int x = v;
#pragma unroll
    for (int off = 1; off < 64; off <<= 1) {
        int tt = __shfl_up(x, off, 64);
        if (lane >= off) x += tt;
    }
    if (lane == 63) wsum[w] = x;
    __syncthreads();
    int wbase = 0;
    for (int k = 0; k < w; k++) wbase += wsum[k];
    int excl = base + wbase + x - v;
    if (i < NN) {
        offs[i] = excl;
        if (i == NN - 1) offs[NN] = excl + v;
    }
}

__global__ void scatter_kernel(const int* __restrict__ srcArr, const int* __restrict__ dstArr,
                               const int* __restrict__ offs, const int* __restrict__ rank,
                               int* __restrict__ csr) {
    int i = blockIdx.x * blockDim.x + threadIdx.x;
    if (i < ETOT) {
        int s, d;
        if (i < NE) {
            s = srcArr[i];
            d = dstArr[i];
        } else {
            s = d = i - NE;
        }
        csr[offs[d] + rank[i]] = s;
    }
}

// ---- layer-1 GEMM v4: 32-row x 256-col tiles, grid=1564 (~6 blocks/CU),
//      x read once, fp32->bf16 in-register staging, al1 epilogue ------------
__global__ __launch_bounds__(256) void gemm1_fused(
        const float* __restrict__ X, const __bf16* __restrict__ B,
        __bf16* __restrict__ C, const float* __restrict__ a_s,
        const float* __restrict__ a_d, float* __restrict__ alsrc,
        float* __restrict__ aldst) {
    __shared__ __bf16 As[32 * LDP];
    __shared__ __bf16 Bs[256 * LDP];
    int tid = threadIdx.x;
    int lane = tid & 63, wid = tid >> 6;
    int quad = lane >> 4, l15 = lane & 15;
    int wn = wid * 64;               // each wave: 32 rows x 64 cols (one head)
    long row0 = (long)blockIdx.x * 32;
    v4f acc[2][4] = {};
    for (int k0 = 0; k0 < 256; k0 += 32) {
        if (tid < 128) {  // stage A: 32 rows x 32 k, fp32 -> bf16
            int r = tid >> 2, q = tid & 3;
            long row = row0 + r;
            union { __bf16 hh[8]; uint4 u; } pk;
            if (row < NN) {
                const float4* p = (const float4*)(X + row * ICH + k0 + q * 8);
                float4 f0 = p[0], f1 = p[1];
                pk.hh[0] = (__bf16)f0.x; pk.hh[1] = (__bf16)f0.y;
                pk.hh[2] = (__bf16)f0.z; pk.hh[3] = (__bf16)f0.w;
                pk.hh[4] = (__bf16)f1.x; pk.hh[5] = (__bf16)f1.y;
                pk.hh[6] = (__bf16)f1.z; pk.hh[7] = (__bf16)f1.w;
            } else {
                pk.u = uint4{0u, 0u, 0u, 0u};
            }
            *(uint4*)(&As[r * LDP + q * 8]) = pk.u;
        }
#pragma unroll
        for (int t = 0; t < 4; t++) {  // stage B: 256 cols x 32 k
            int i = tid + t * 256;
            int r = i >> 2, q = i & 3;
            *(uint4*)(&Bs[r * LDP + q * 8]) = *(const uint4*)(B + (size_t)r * 256 + k0 + q * 8);
        }
        __syncthreads();
        v8bf af[2], bfr[4];
#pragma unroll
        for (int t = 0; t < 2; t++)
            af[t] = *(const v8bf*)(&As[(t * 16 + l15) * LDP + quad * 8]);
#pragma unroll
        for (int t = 0; t < 4; t++)
            bfr[t] = *(const v8bf*)(&Bs[(wn + t * 16 + l15) * LDP + quad * 8]);
#pragma unroll
        for (int mi = 0; mi < 2; mi++)
#pragma unroll
            for (int ni = 0; ni < 4; ni++)
                acc[mi][ni] = __builtin_amdgcn_mfma_f32_16x16x32_bf16(af[mi], bfr[ni], acc[mi][ni], 0, 0, 0);
        __syncthreads();
    }
#pragma unroll
    for (int mi = 0; mi < 2; mi++)
#pragma unroll
        for (int ni = 0; ni < 4; ni++)
#pragma unroll
            for (int r = 0; r < 4; r++) {
                long row = row0 + mi * 16 + quad * 4 + r;
                C[row * ICH + wn + ni * 16 + l15] = (__bf16)acc[mi][ni][r];
            }
    // fused al1: this wave's 64 cols are exactly one head
    int head = wn >> 6;
    float asv[4], adv[4];
#pragma unroll
    for (int ni = 0; ni < 4; ni++) {
        int cc = wn + ni * 16 + l15;
        asv[ni] = a_s[cc];
        adv[ni] = a_d[cc];
    }
#pragma unroll
    for (int mi = 0; mi < 2; mi++)
#pragma unroll
        for (int r = 0; r < 4; r++) {
            float vs = 0.f, vd = 0.f;
#pragma unroll
            for (int ni = 0; ni < 4; ni++) {
                vs += acc[mi][ni][r] * asv[ni];
                vd += acc[mi][ni][r] * adv[ni];
            }
#pragma unroll
            for (int m = 1; m <= 8; m <<= 1) {
                vs += __shfl_xor(vs, m, 64);
                vd += __shfl_xor(vd, m, 64);
            }
            long row = row0 + mi * 16 + quad * 4 + r;
            if (l15 == 0 && row < NN) {
                alsrc[row * HEADS + head] = vs;
                aldst[row * HEADS + head] = vd;
            }
        }
}

// ---- layer-2 GEMM v4: 32-row x 128-col tiles, grid=1564; compact 40-col C;
//      al2 epilogue --------------------------------------------------------
__global__ __launch_bounds__(256) void gemm2_fused(
        const __bf16* __restrict__ A, const __bf16* __restrict__ B,
        __bf16* __restrict__ C, const float* __restrict__ a_s,
        const float* __restrict__ a_d, float* __restrict__ alsrc,
        float* __restrict__ aldst) {
    __shared__ __bf16 As[32 * LDP];
    __shared__ __bf16 Bs[128 * LDP];
    int tid = threadIdx.x;
    int lane = tid & 63, wid = tid >> 6;
    int quad = lane >> 4, l15 = lane & 15;
    int wm = (wid >> 1) * 16, wn = (wid & 1) * 64;  // wave: 16 rows x 64 cols
    long row0 = (long)blockIdx.x * 32;
    v4f acc[4] = {};
    for (int k0 = 0; k0 < 256; k0 += 32) {
        if (tid < 128) {  // stage A: 32 rows x 32 k (bf16 passthrough)
            int r = tid >> 2, q = tid & 3;
            *(uint4*)(&As[r * LDP + q * 8]) = *(const uint4*)(A + (row0 + r) * 256 + k0 + q * 8);
        }
#pragma unroll
        for (int t = 0; t < 2; t++) {  // stage B: 128 cols x 32 k
            int i = tid + t * 256;
            int r = i >> 2, q = i & 3;
            *(uint4*)(&Bs[r * LDP + q * 8]) = *(const uint4*)(B + (size_t)r * 256 + k0 + q * 8);
        }
        __syncthreads();
        v8bf af, bfr[4];
        af = *(const v8bf*)(&As[(wm + l15) * LDP + quad * 8]);
#pragma unroll
        for (int t = 0; t < 4; t++)
            bfr[t] = *(const v8bf*)(&Bs[(wn + t * 16 + l15) * LDP + quad * 8]);
#pragma unroll
        for (int ni = 0; ni < 4; ni++)
            acc[ni] = __builtin_amdgcn_mfma_f32_16x16x32_bf16(af, bfr[ni], acc[ni], 0, 0, 0);
        __syncthreads();
    }
#pragma unroll
    for (int ni = 0; ni < 4; ni++)
#pragma unroll
        for (int r = 0; r < 4; r++) {
            long row = row0 + wm + quad * 4 + r;
            int col = wn + ni * 16 + l15;
            if (col < OCH) C[row * OCH + col] = (__bf16)acc[ni][r];
        }
    if (wn == 0) {  // al2: wid 0 covers rows 0..15, wid 2 covers rows 16..31
        float asv[4], adv[4];
#pragma unroll
        for (int ni = 0; ni < 4; ni++) {
            int c = ni * 16 + l15;
            bool on = c < OCH;
            asv[ni] = on ? a_s[c] : 0.f;
            adv[ni] = on ? a_d[c] : 0.f;
        }
#pragma unroll
        for (int r = 0; r < 4; r++) {
            float vs = 0.f, vd = 0.f;
#pragma unroll
            for (int ni = 0; ni < 4; ni++) {
                vs += acc[ni][r] * asv[ni];
                vd += acc[ni][r] * adv[ni];
            }
#pragma unroll
            for (int m = 1; m <= 8; m <<= 1) {
                vs += __shfl_xor(vs, m, 64);
                vd += __shfl_xor(vd, m, 64);
            }
            long row = row0 + wm + quad * 4 + r;
            if (l15 == 0 && row < NN) {
                alsrc[row] = vs;
                aldst[row] = vd;
            }
        }
    }
}

// -------- layer-1 aggregation: wave/dst; 2 edge-slots x 32 cg; pipelined ---
__global__ __launch_bounds__(256) void aggregate1(
        const int* __restrict__ offs, const int* __restrict__ csr,
        const __bf16* __restrict__ h, const float* __restrict__ alsrc,
        const float* __restrict__ aldst, const float* __restrict__ bias,
        __bf16* __restrict__ z) {
    int lane = threadIdx.x & 63, wid = threadIdx.x >> 6;
    int d = blockIdx.x * 4 + wid;
    if (d >= MPAD) return;
    int es = lane >> 5;
    int cg = lane & 31;
    if (d >= NN) {
        if (es == 0) *(uint4*)(z + (size_t)d * ICH + cg * 8) = uint4{0u, 0u, 0u, 0u};
        return;
    }
    int head = cg >> 3;
    int e0 = offs[d], e1 = offs[d + 1];
    float ald = aldst[d * HEADS + head];
    float acc[8] = {};
    float wsum = 0.f;
    int e = e0 + es;
    int sA = (e < e1) ? csr[e] : 0;
    float alA = alsrc[sA * HEADS + head];
    v8bf hvA = *(const v8bf*)(h + (size_t)sA * ICH + cg * 8);
    for (; e < e1; e += 2) {
        int en = e + 2;
        int sB = (en < e1) ? csr[en] : 0;
        float alB = alsrc[sB * HEADS + head];
        v8bf hvB = *(const v8bf*)(h + (size_t)sB * ICH + cg * 8);
        float x = alA + ald;
        x = (x > 0.f) ? x : SLOPE * x;
        float w = __expf(x);
        wsum += w;
#pragma unroll
        for (int j = 0; j < 8; j++) acc[j] += w * (float)hvA[j];
        alA = alB; hvA = hvB;
    }
#pragma unroll
    for (int j = 0; j < 8; j++) acc[j] += __shfl_down(acc[j], 32, 64);
    wsum += __shfl_down(wsum, 32, 64);
    if (es == 0) {
        float inv = 1.f / (wsum + 1e-16f);
        union { __bf16 hh[8]; uint4 u; } p;
#pragma unroll
        for (int j = 0; j < 8; j++) {
            float o = acc[j] * inv + bias[cg * 8 + j];
            o = (o > 0.f) ? o : (__expf(o) - 1.f);  // ELU
            p.hh[j] = (__bf16)o;
        }
        *(uint4*)(z + (size_t)d * ICH + cg * 8) = p.u;
    }
}

// -------- layer-2 aggregation: wave/dst; 8 edge-slots x 8 cg; compact h2 ---
__global__ __launch_bounds__(256) void aggregate2(
        const int* __restrict__ offs, const int* __restrict__ csr,
        const __bf16* __restrict__ h2, const float* __restrict__ alsrc,
        const float* __restrict__ aldst, const float* __restrict__ bias,
        float* __restrict__ out) {
    int lane = threadIdx.x & 63, wid = threadIdx.x >> 6;
    int d = blockIdx.x * 4 + wid;
    if (d >= NN) return;
    int es = lane >> 3;
    int cg = lane & 7;
    bool on = cg < 5;
    int cgc = on ? cg : 4;
    int e0 = offs[d], e1 = offs[d + 1];
    float ald = aldst[d];
    float acc[8] = {};
    float wsum = 0.f;
    int e = e0 + es;
    int sA = (e < e1) ? csr[e] : 0;
    float alA = alsrc[sA];
    v8bf hvA = *(const v8bf*)(h2 + (size_t)sA * OCH + cgc * 8);
    for (; e < e1; e += 8) {
        int en = e + 8;
        int sB = (en < e1) ? csr[en] : 0;
        float alB = alsrc[sB];
        v8bf hvB = *(const v8bf*)(h2 + (size_t)sB * OCH + cgc * 8);
        float x = alA + ald;
        x = (x > 0.f) ? x : SLOPE * x;
        float w = __expf(x);
        wsum += w;
#pragma unroll
        for (int j = 0; j < 8; j++) acc[j] += w * (float)hvA[j];
        alA = alB; hvA = hvB;
    }
#pragma unroll
    for (int m = 8; m <= 32; m <<= 1) {
#pragma unroll
        for (int j = 0; j < 8; j++) acc[j] += __shfl_xor(acc[j], m, 64);
        wsum += __shfl_xor(wsum, m, 64);
    }
    if (es == 0 && on) {
        float inv = 1.f / (wsum + 1e-16f);
#pragma unroll
        for (int j = 0; j < 8; j++)
            out[(size_t)d * OCH + cg * 8 + j] = acc[j] * inv + bias[cg * 8 + j];
    }
}

extern "C" void kernel_launch(void* const* d_in, const int* in_sizes, int n_in,
                              void* d_out, int out_size, void* d_ws, size_t ws_size,
                              hipStream_t stream) {
    const float* x   = (const float*)d_in[0];
    const int*   ei  = (const int*)d_in[1];
    const float* W1  = (const float*)d_in[2];
    const float* as1 = (const float*)d_in[3];
    const float* ad1 = (const float*)d_in[4];
    const float* b1  = (const float*)d_in[5];
    const float* W2  = (const float*)d_in[6];
    const float* as2 = (const float*)d_in[7];
    const float* ad2 = (const float*)d_in[8];
    const float* b2  = (const float*)d_in[9];
    float* out = (float*)d_out;

    char* ws = (char*)d_ws;
    size_t o = 0;
    auto alloc = [&](size_t bytes) {
        void* p = ws + o;
        o += (bytes + 255) & ~(size_t)255;
        return p;
    };
    __bf16* h1    = (__bf16*)alloc((size_t)MPAD * ICH * 2);
    __bf16* z     = (__bf16*)alloc((size_t)MPAD * ICH * 2);
    __bf16* h2    = (__bf16*)alloc((size_t)MPAD * OCH * 2);
    __bf16* W1T   = (__bf16*)alloc((size_t)256 * 256 * 2);
    __bf16* W2T   = (__bf16*)alloc((size_t)128 * 256 * 2);
    float* alsrc1 = (float*)alloc((size_t)NN * HEADS * 4);
    float* aldst1 = (float*)alloc((size_t)NN * HEADS * 4);
    float* alsrc2 = (float*)alloc((size_t)NN * 4);
    float* aldst2 = (float*)alloc((size_t)NN * 4);
    int*   deg    = (int*)alloc((size_t)NN * 4);
    int*   offs   = (int*)alloc((size_t)(NN + 1) * 4);
    int*   csr    = (int*)alloc((size_t)ETOT * 4);
    int*   rank   = (int*)alloc((size_t)ETOT * 4);
    int*   bsum   = (int*)alloc((size_t)SCAN_B * 4);

    const int* srcArr = ei;
    const int* dstArr = ei + NE;

    // deg must be zero before prep's hist branch
    hipMemsetAsync(deg, 0, (size_t)NN * 4, stream);

    // prep: transW || hist (task-parallel block ranges)
    prep_kernel<<<384 + HB, 256, 0, stream>>>(W1, W2, W1T, W2T, dstArr, deg, rank);
    blocksum_kernel<<<SCAN_B, 256, 0, stream>>>(deg, bsum);
    scan_final<<<SCAN_B, 256, 0, stream>>>(deg, bsum, offs);
    scatter_kernel<<<HB, 256, 0, stream>>>(srcArr, dstArr, offs, rank, csr);

    // Layer 1 (32-row tiles, grid 1564, x read once, al1 fused)
    gemm1_fused<<<MPAD / 32, 256, 0, stream>>>(x, W1T, h1, as1, ad1, alsrc1, aldst1);
    aggregate1<<<MPAD / 4, 256, 0, stream>>>(offs, csr, h1, alsrc1, aldst1, b1, z);

    // Layer 2 (32-row tiles, grid 1564, compact h2, al2 fused)
    gemm2_fused<<<MPAD / 32, 256, 0, stream>>>(z, W2T, h2, as2, ad2, alsrc2, aldst2);
    aggregate2<<<(NN + 3) / 4, 256, 0, stream>>>(offs, csr, h2, alsrc2, aldst2, b2, out);
}